// Round 19
// baseline (33.997 us; speedup 1.0000x reference)
//
#include <hip/hip_runtime.h>
#include <hip/hip_bf16.h>
#include <math.h>

#define NNODE 120000
#define DDIM  128
#define SS    100
#define NNEGS 50
#define ROWS_A 1600    // anchor/positive rows per type: slice(4) x idset(4) x 100
#define ROWS_N 20000   // cross-neg rows per type: vl(4) x s(100) x n(50)
#define TOTAL_ROWS 43200
#define NBLK 338                             // 338 x 128 rows = 43264 (pad clamps)
#define ZPAD_BYTES (43264 * 256)
#define WFRAG_SHORTS 16384                   // per layer: kc(4) x ct(8) x lane(64) x 8
#define HSTRIDE 136                          // ushorts: 272 B slab row stride (affine, ~2-way)
#define INV_TEMP 2.0f

typedef unsigned short ushort_t;
typedef __attribute__((ext_vector_type(8))) short bf16x8;
typedef __attribute__((ext_vector_type(8))) unsigned short u16x8;
typedef __attribute__((ext_vector_type(4))) float f32x4;

// HW bf16 convert (RNE) — compiler packs pairs into v_cvt_pk_bf16_f32
__device__ __forceinline__ ushort_t f2b(float f) {
  __hip_bfloat16 h = __float2bfloat16(f);
  return *reinterpret_cast<ushort_t*>(&h);
}
__device__ __forceinline__ float b2f(ushort_t h) {
  return __builtin_bit_cast(float, (unsigned)h << 16);
}
__device__ __forceinline__ bool idx_is64(const void* p) {
  const unsigned* q = (const unsigned*)p;
  return (q[1] | q[3] | q[5] | q[7]) == 0u;
}
__device__ __forceinline__ int ld_idx(const void* p, int i, bool is64) {
  return is64 ? (int)((const long long*)p)[i] : ((const int*)p)[i];
}

// zrows layout (bf16 rows of 128):
//   [0,1600) A_p | [1600,3200) A_c | [3200,23200) N_pc | [23200,43200) N_cp | pad
__device__ __forceinline__ const float* row_src(
    int rid, bool is64,
    const float* emb_p, const float* emb_c,
    const void* idx_p, const void* idx_c,
    const void* nidx_p, const void* nidx_c)
{
  if (rid < 2 * ROWS_A) {
    const int typ = rid / ROWS_A;
    const int rr  = rid - typ * ROWS_A;
    const int slice = rr / 400;
    const int rem   = rr - slice * 400;          // idset*100 + s
    const int node  = ld_idx(typ ? idx_c : idx_p, rem, is64);
    return (typ ? emb_c : emb_p) + ((size_t)slice * NNODE + node) * DDIM;
  } else {
    const int r2  = rid - 2 * ROWS_A;
    const int typ = r2 / ROWS_N;
    const int rr  = r2 - typ * ROWS_N;
    const int slice = rr / (SS * NNEGS);
    const int rem   = rr - slice * (SS * NNEGS);
    const int node  = ld_idx(typ ? nidx_c : nidx_p, slice * (SS * NNEGS) + rem, is64);
    return (typ ? emb_p : emb_c) + ((size_t)slice * NNODE + node) * DDIM;
  }
}

// W -> B-fragment order in GLOBAL (bf16): frag[layer][kc][ct][lane][e] =
//   W[kc*32 + 8*(lane>>4) + e][ct*16 + (lane&15)]   (R4-verified layout, HW casts)
__global__ __launch_bounds__(64)
void wfrag_kernel(const float* __restrict__ W1, const float* __restrict__ W2,
                  ushort_t* __restrict__ wfrag, float* __restrict__ out)
{
  if (blockIdx.x == 0 && threadIdx.x == 0) out[0] = 0.f;   // fold out-zero
  const int b = blockIdx.x;                 // 64 = layer(2) x kc(4) x ct(8)
  const int layer = b >> 5, kc = (b >> 3) & 3, ct = b & 7;
  const int l = threadIdx.x;
  const float* W = layer ? W2 : W1;
  ushort_t* dst = wfrag + layer * WFRAG_SHORTS + (size_t)((kc * 8 + ct) * 64 + l) * 8;
  const int col   = ct * 16 + (l & 15);
  const int krow0 = kc * 32 + ((l >> 4) << 3);
  #pragma unroll
  for (int e = 0; e < 8; ++e)
    dst[e] = f2b(W[(size_t)(krow0 + e) * DDIM + col]);
}

// ---- proj: BARRIER-FREE. B-frags streamed from L2 per MFMA; LDS only for the
// per-wave H/z slab (34 KB/block). 4 waves x 32 rows per block. ----
__global__ __launch_bounds__(256)
void proj_kernel(const float* __restrict__ emb_p, const float* __restrict__ emb_c,
                 const float* __restrict__ b1v, const float* __restrict__ b2v,
                 const void* __restrict__ idx_p, const void* __restrict__ idx_c,
                 const void* __restrict__ nidx_p, const void* __restrict__ nidx_c,
                 const ushort_t* __restrict__ wfrag,
                 ushort_t* __restrict__ zout)
{
  __shared__ __align__(16) ushort_t slab[4 * 32 * HSTRIDE];   // 34816 B, wave-private 32-row regions
  const int t = threadIdx.x, w = t >> 6, l = t & 63;
  const int g = l >> 4, li = l & 15;
  const bool is64 = idx_is64(idx_p);
  const int base = blockIdx.x * 128;
  ushort_t* slw = &slab[w * 32 * HSTRIDE];   // this wave's region

  // ---- gather this wave's 32 rows (2 per thread) into A-fragments ----
  int rida = base + w * 32 + li;
  int ridb = rida + 16;
  if (rida > TOTAL_ROWS - 1) rida = TOTAL_ROWS - 1;
  if (ridb > TOTAL_ROWS - 1) ridb = TOTAL_ROWS - 1;
  const float* sa = row_src(rida, is64, emb_p, emb_c, idx_p, idx_c, nidx_p, nidx_c);
  const float* sb = row_src(ridb, is64, emb_p, emb_c, idx_p, idx_c, nidx_p, nidx_c);
  bf16x8 afa[4], afb[4];
  #pragma unroll
  for (int kc = 0; kc < 4; ++kc) {
    const float4 a0 = *(const float4*)(sa + kc * 32 + g * 8);
    const float4 a1 = *(const float4*)(sa + kc * 32 + g * 8 + 4);
    const float4 b0 = *(const float4*)(sb + kc * 32 + g * 8);
    const float4 b1 = *(const float4*)(sb + kc * 32 + g * 8 + 4);
    bf16x8 fa, fb;
    fa[0]=(short)f2b(a0.x); fa[1]=(short)f2b(a0.y); fa[2]=(short)f2b(a0.z); fa[3]=(short)f2b(a0.w);
    fa[4]=(short)f2b(a1.x); fa[5]=(short)f2b(a1.y); fa[6]=(short)f2b(a1.z); fa[7]=(short)f2b(a1.w);
    fb[0]=(short)f2b(b0.x); fb[1]=(short)f2b(b0.y); fb[2]=(short)f2b(b0.z); fb[3]=(short)f2b(b0.w);
    fb[4]=(short)f2b(b1.x); fb[5]=(short)f2b(b1.y); fb[6]=(short)f2b(b1.z); fb[7]=(short)f2b(b1.w);
    afa[kc] = fa; afb[kc] = fb;
  }

  f32x4 aa[8], ab[8];
  // ---- layer 1: H = relu(X @ W1 + b1); B-frags streamed from global (L1/L2-hot) ----
  #pragma unroll
  for (int ct = 0; ct < 8; ++ct) {
    const float bv = b1v[ct * 16 + li];
    aa[ct] = (f32x4){bv, bv, bv, bv};
    ab[ct] = aa[ct];
  }
  #pragma unroll
  for (int kc = 0; kc < 4; ++kc)
    #pragma unroll
    for (int ct = 0; ct < 8; ++ct) {
      const bf16x8 bf = *(const bf16x8*)&wfrag[((kc * 8 + ct) * 64 + l) * 8];
      aa[ct] = __builtin_amdgcn_mfma_f32_16x16x32_bf16(afa[kc], bf, aa[ct], 0, 0, 0);
      ab[ct] = __builtin_amdgcn_mfma_f32_16x16x32_bf16(afb[kc], bf, ab[ct], 0, 0, 0);
    }
  // relu -> own slab rows (affine 272B stride; wave-private, in-order DS)
  #pragma unroll
  for (int rg = 0; rg < 4; ++rg) {
    ushort_t* rowpa = &slw[(4 * g + rg) * HSTRIDE + li];
    ushort_t* rowpb = rowpa + 16 * HSTRIDE;
    #pragma unroll
    for (int ct = 0; ct < 8; ++ct) {
      rowpa[ct * 16] = f2b(fmaxf(aa[ct][rg], 0.f));
      rowpb[ct * 16] = f2b(fmaxf(ab[ct][rg], 0.f));
    }
  }
  // ---- layer 2: Z = H @ W2 + b2 ----
  #pragma unroll
  for (int ct = 0; ct < 8; ++ct) {
    const float bv = b2v[ct * 16 + li];
    aa[ct] = (f32x4){bv, bv, bv, bv};
    ab[ct] = aa[ct];
  }
  {
    const ushort_t* rowa = &slw[li * HSTRIDE + g * 8];
    const ushort_t* rowb = rowa + 16 * HSTRIDE;
    #pragma unroll
    for (int kc = 0; kc < 4; ++kc) {
      const bf16x8 hfa = *(const bf16x8*)(rowa + kc * 32);
      const bf16x8 hfb = *(const bf16x8*)(rowb + kc * 32);
      #pragma unroll
      for (int ct = 0; ct < 8; ++ct) {
        const bf16x8 bf = *(const bf16x8*)&wfrag[WFRAG_SHORTS + ((kc * 8 + ct) * 64 + l) * 8];
        aa[ct] = __builtin_amdgcn_mfma_f32_16x16x32_bf16(hfa, bf, aa[ct], 0, 0, 0);
        ab[ct] = __builtin_amdgcn_mfma_f32_16x16x32_bf16(hfb, bf, ab[ct], 0, 0, 0);
      }
    }
  }
  // ---- L2 norm per sample group ----
  #pragma unroll
  for (int grp = 0; grp < 2; ++grp) {
    f32x4* ac = grp ? ab : aa;
    float sc[4];
    #pragma unroll
    for (int rg = 0; rg < 4; ++rg) {
      float ssq = 0.f;
      #pragma unroll
      for (int ct = 0; ct < 8; ++ct) ssq += ac[ct][rg] * ac[ct][rg];
      ssq += __shfl_xor(ssq, 1);
      ssq += __shfl_xor(ssq, 2);
      ssq += __shfl_xor(ssq, 4);
      ssq += __shfl_xor(ssq, 8);
      sc[rg] = 1.f / fmaxf(sqrtf(ssq), 1e-12f);
    }
    #pragma unroll
    for (int rg = 0; rg < 4; ++rg) {
      ushort_t* rowp = &slw[(grp * 16 + 4 * g + rg) * HSTRIDE + li];
      #pragma unroll
      for (int ct = 0; ct < 8; ++ct)
        rowp[ct * 16] = f2b(ac[ct][rg] * sc[rg]);
    }
  }
  // coalesced copy-out of own 32 rows (strided slab -> dense global; no barrier)
  {
    uint4* d4 = (uint4*)(zout + (size_t)(base + w * 32) * DDIM);
    const uint4* s4 = (const uint4*)slw;
    #pragma unroll
    for (int i = 0; i < 8; ++i) {
      const int e = l + 64 * i;                 // 512 uint4 chunks over 32 rows
      const int row = e >> 4, c = e & 15;
      d4[e] = s4[row * (HSTRIDE / 8) + c];
    }
  }
}

// ---- loss: R17 exactly (104 blocks x 512; slice in LDS; 1 atomic/block) ----
#define LROW_U4 17                           // 272 B row stride in uint4 units
__global__ __launch_bounds__(512)
void loss_kernel(const ushort_t* __restrict__ zb, float* __restrict__ out)
{
  __shared__ __align__(16) uint4 sl[SS * LROW_U4];     // 27200 B slice stage
  __shared__ float sterm[8];
  const int bid = blockIdx.x;            // 104 = chunk(13) x grp(8), grp fastest
  const int grp = bid & 7;               // XCD-affine under round-robin dispatch
  const int chunk = bid >> 3;
  const int typ = grp >> 2;
  const int vl  = grp & 3;
  const ushort_t* A  = zb + (size_t)(typ ? ROWS_A : 0) * DDIM;
  const ushort_t* Nb = zb + (size_t)(2 * ROWS_A + (typ ? ROWS_N : 0)) * DDIM;
  const ushort_t* SL = A + (size_t)(vl * 4 + vl) * SS * DDIM;  // anchor slice
  const int t = threadIdx.x, l = t & 63, w = t >> 6;
  const int tsub = l >> 3, eg = l & 7;
  const int s_raw = chunk * 8 + w;
  const bool act = (s_raw < SS);
  const int s = act ? s_raw : SS - 1;

  #pragma unroll
  for (int i = 0; i < 4; ++i) {
    const int c = i * 512 + t;                 // 1600 uint4 chunks
    if (c < SS * 16)
      sl[(c >> 4) * LROW_U4 + (c & 15)] = ((const uint4*)SL)[c];
  }

  const ushort_t* zs = SL + (size_t)s * DDIM;
  float zr[16];
  {
    const u16x8 v0 = *(const u16x8*)(zs + eg * 16);
    const u16x8 v1 = *(const u16x8*)(zs + eg * 16 + 8);
    #pragma unroll
    for (int j = 0; j < 8; ++j) { zr[j] = b2f(v0[j]); zr[j + 8] = b2f(v1[j]); }
  }

  float pe = 0.f, ne = 0.f;
  // target order: [0,50) cross | [50,53) pos | [53,152) within
  #pragma unroll
  for (int pass = 0; pass < 6; ++pass) {
    const int n = pass * 8 + tsub;
    const ushort_t* tp = Nb + (size_t)((vl * SS + s) * NNEGS + n) * DDIM;
    const u16x8 x0 = *(const u16x8*)(tp + eg * 16);
    const u16x8 x1 = *(const u16x8*)(tp + eg * 16 + 8);
    float d = 0.f;
    #pragma unroll
    for (int j = 0; j < 8; ++j) {
      d = fmaf(b2f(x0[j]), zr[j], d);
      d = fmaf(b2f(x1[j]), zr[j + 8], d);
    }
    d += __shfl_xor(d, 1);
    d += __shfl_xor(d, 2);
    d += __shfl_xor(d, 4);
    ne += __expf(d * INV_TEMP);
  }
  __syncthreads();                             // slice staged

  #pragma unroll
  for (int pass = 6; pass < 19; ++pass) {
    const int tt = pass * 8 + tsub;
    float d = 0.f;
    bool is_pos = false;
    if (tt >= 53) {                            // within-neg from LDS
      int j = tt - 53;
      int t2 = j + (j >= s ? 1 : 0);
      const uint4* rp = &sl[t2 * LROW_U4 + eg * 2];
      const u16x8 x0 = *(const u16x8*)rp;
      const u16x8 x1 = *(const u16x8*)(rp + 1);
      #pragma unroll
      for (int j2 = 0; j2 < 8; ++j2) {
        d = fmaf(b2f(x0[j2]), zr[j2], d);
        d = fmaf(b2f(x1[j2]), zr[j2 + 8], d);
      }
    } else {
      const ushort_t* tp;
      if (tt < 50) {
        tp = Nb + (size_t)((vl * SS + s) * NNEGS + tt) * DDIM;
      } else {
        const int kp = tt - 50;
        const int k = kp + (kp >= vl ? 1 : 0);
        tp = A + (size_t)((k * 4 + vl) * SS + s) * DDIM;
        is_pos = true;
      }
      const u16x8 x0 = *(const u16x8*)(tp + eg * 16);
      const u16x8 x1 = *(const u16x8*)(tp + eg * 16 + 8);
      #pragma unroll
      for (int j2 = 0; j2 < 8; ++j2) {
        d = fmaf(b2f(x0[j2]), zr[j2], d);
        d = fmaf(b2f(x1[j2]), zr[j2 + 8], d);
      }
    }
    d += __shfl_xor(d, 1);
    d += __shfl_xor(d, 2);
    d += __shfl_xor(d, 4);
    const float e = __expf(d * INV_TEMP);
    if (is_pos) pe += e; else ne += e;
  }
  pe += __shfl_xor(pe, 8);  ne += __shfl_xor(ne, 8);
  pe += __shfl_xor(pe, 16); ne += __shfl_xor(ne, 16);
  pe += __shfl_xor(pe, 32); ne += __shfl_xor(ne, 32);
  if (l == 0) sterm[w] = act ? -logf(pe / (pe + ne)) : 0.f;
  __syncthreads();
  if (t == 0) {
    float tot = 0.f;
    #pragma unroll
    for (int i = 0; i < 8; ++i) tot += sterm[i];
    atomicAdd(out, tot * (1.0f / 800.0f));
  }
}

extern "C" void kernel_launch(void* const* d_in, const int* in_sizes, int n_in,
                              void* d_out, int out_size, void* d_ws, size_t ws_size,
                              hipStream_t stream) {
  const float* emb_p = (const float*)d_in[0];
  const float* emb_c = (const float*)d_in[1];
  const float* W1    = (const float*)d_in[2];
  const float* b1    = (const float*)d_in[3];
  const float* W2    = (const float*)d_in[4];
  const float* b2    = (const float*)d_in[5];
  const void*  idx_p  = d_in[6];
  const void*  idx_c  = d_in[7];
  const void*  nidx_p = d_in[8];
  const void*  nidx_c = d_in[9];
  float* out = (float*)d_out;
  ushort_t* zrows = (ushort_t*)d_ws;
  ushort_t* wfrag = (ushort_t*)((char*)d_ws + ZPAD_BYTES);

  wfrag_kernel<<<64, 64, 0, stream>>>(W1, W2, wfrag, out);
  proj_kernel<<<NBLK, 256, 0, stream>>>(
      emb_p, emb_c, b1, b2, idx_p, idx_c, nidx_p, nidx_c, wfrag, zrows);
  loss_kernel<<<104, 512, 0, stream>>>(zrows, out);
}

// Round 20
// 28.032 us; speedup vs baseline: 1.2128x; 1.2128x over previous
//
#include <hip/hip_runtime.h>
#include <hip/hip_bf16.h>
#include <math.h>

#define NNODE 120000
#define DDIM  128
#define SS    100
#define NNEGS 50
#define ROWS_A 1600    // anchor/positive rows per type: slice(4) x idset(4) x 100
#define ROWS_N 20000   // cross-neg rows per type: vl(4) x s(100) x n(50)
#define TOTAL_ROWS 43200
#define BLK_ROWS 256
#define NBLK 169                             // 169 x 256 = 43264 (pad clamps)
#define HSTRIDE 136                          // ushorts: 272 B row stride (bank-safe, affine)
#define INV_TEMP 2.0f

typedef unsigned short ushort_t;
typedef __attribute__((ext_vector_type(8))) short bf16x8;
typedef __attribute__((ext_vector_type(8))) unsigned short u16x8;
typedef __attribute__((ext_vector_type(4))) float f32x4;

// HW bf16 convert (RNE) — compiler packs pairs into v_cvt_pk_bf16_f32
__device__ __forceinline__ ushort_t f2b(float f) {
  __hip_bfloat16 h = __float2bfloat16(f);
  return *reinterpret_cast<ushort_t*>(&h);
}
__device__ __forceinline__ float b2f(ushort_t h) {
  return __builtin_bit_cast(float, (unsigned)h << 16);
}
__device__ __forceinline__ bool idx_is64(const void* p) {
  const unsigned* q = (const unsigned*)p;
  return (q[1] | q[3] | q[5] | q[7]) == 0u;
}
__device__ __forceinline__ int ld_idx(const void* p, int i, bool is64) {
  return is64 ? (int)((const long long*)p)[i] : ((const int*)p)[i];
}

// zrows layout (bf16 rows of 128):
//   [0,1600) A_p | [1600,3200) A_c | [3200,23200) N_pc | [23200,43200) N_cp | pad
__device__ __forceinline__ const float* row_src(
    int rid, bool is64,
    const float* emb_p, const float* emb_c,
    const void* idx_p, const void* idx_c,
    const void* nidx_p, const void* nidx_c)
{
  if (rid < 2 * ROWS_A) {
    const int typ = rid / ROWS_A;
    const int rr  = rid - typ * ROWS_A;
    const int slice = rr / 400;
    const int rem   = rr - slice * 400;          // idset*100 + s
    const int node  = ld_idx(typ ? idx_c : idx_p, rem, is64);
    return (typ ? emb_c : emb_p) + ((size_t)slice * NNODE + node) * DDIM;
  } else {
    const int r2  = rid - 2 * ROWS_A;
    const int typ = r2 / ROWS_N;
    const int rr  = r2 - typ * ROWS_N;
    const int slice = rr / (SS * NNEGS);
    const int rem   = rr - slice * (SS * NNEGS);
    const int node  = ld_idx(typ ? nidx_c : nidx_p, slice * (SS * NNEGS) + rem, is64);
    return (typ ? emb_p : emb_c) + ((size_t)slice * NNODE + node) * DDIM;
  }
}

// ---- proj: R15/R17 structure; H/z slab in 272B-stride affine rows ----
__global__ __launch_bounds__(512, 1)
void proj_kernel(const float* __restrict__ emb_p, const float* __restrict__ emb_c,
                 const float* __restrict__ W1, const float* __restrict__ b1v,
                 const float* __restrict__ W2, const float* __restrict__ b2v,
                 const void* __restrict__ idx_p, const void* __restrict__ idx_c,
                 const void* __restrict__ nidx_p, const void* __restrict__ nidx_c,
                 ushort_t* __restrict__ zout, float* __restrict__ out)
{
  __shared__ __align__(16) ushort_t wlds[2 * 16384];            // 64 KB: W1+W2 frags
  __shared__ __align__(16) ushort_t slab[BLK_ROWS * HSTRIDE];   // 68 KB: 272B-stride rows
  const int t = threadIdx.x, w = t >> 6, l = t & 63;
  const int g = l >> 4, li = l & 15;
  const bool is64 = idx_is64(idx_p);
  const int base = blockIdx.x * BLK_ROWS;
  const int ra = w * 32 + li;
  const int rb = ra + 16;

  if (blockIdx.x == 0 && t == 0) out[0] = 0.f;

  int rida = base + ra, ridb = base + rb;
  if (rida > TOTAL_ROWS - 1) rida = TOTAL_ROWS - 1;
  if (ridb > TOTAL_ROWS - 1) ridb = TOTAL_ROWS - 1;
  const float* sa = row_src(rida, is64, emb_p, emb_c, idx_p, idx_c, nidx_p, nidx_c);
  const float* sb = row_src(ridb, is64, emb_p, emb_c, idx_p, idx_c, nidx_p, nidx_c);
  bf16x8 afa[4], afb[4];
  #pragma unroll
  for (int kc = 0; kc < 4; ++kc) {
    const float4 a0 = *(const float4*)(sa + kc * 32 + g * 8);
    const float4 a1 = *(const float4*)(sa + kc * 32 + g * 8 + 4);
    const float4 b0 = *(const float4*)(sb + kc * 32 + g * 8);
    const float4 b1 = *(const float4*)(sb + kc * 32 + g * 8 + 4);
    bf16x8 fa, fb;
    fa[0]=(short)f2b(a0.x); fa[1]=(short)f2b(a0.y); fa[2]=(short)f2b(a0.z); fa[3]=(short)f2b(a0.w);
    fa[4]=(short)f2b(a1.x); fa[5]=(short)f2b(a1.y); fa[6]=(short)f2b(a1.z); fa[7]=(short)f2b(a1.w);
    fb[0]=(short)f2b(b0.x); fb[1]=(short)f2b(b0.y); fb[2]=(short)f2b(b0.z); fb[3]=(short)f2b(b0.w);
    fb[4]=(short)f2b(b1.x); fb[5]=(short)f2b(b1.y); fb[6]=(short)f2b(b1.z); fb[7]=(short)f2b(b1.w);
    afa[kc] = fa; afb[kc] = fb;
  }

  #pragma unroll
  for (int p = 0; p < 8; ++p) {
    const int s = p * 512 + t;
    const int layer = s >> 11;
    const int idx = s & 2047;
    const int lane = idx & 63, kcct = idx >> 6;
    const int kc = kcct >> 3, ct = kcct & 7;
    const float* W = layer ? W2 : W1;
    const float* wp = W + (size_t)(kc * 32 + ((lane >> 4) << 3)) * DDIM
                        + ct * 16 + (lane & 15);
    u16x8 v;
    #pragma unroll
    for (int e = 0; e < 8; ++e) v[e] = f2b(wp[(size_t)e * DDIM]);
    *(u16x8*)&wlds[(size_t)s * 8] = v;
  }
  __syncthreads();

  f32x4 aa[8], ab[8];
  #pragma unroll
  for (int ct = 0; ct < 8; ++ct) {
    const float bv = b1v[ct * 16 + li];
    aa[ct] = (f32x4){bv, bv, bv, bv};
    ab[ct] = aa[ct];
  }
  #pragma unroll
  for (int kc = 0; kc < 4; ++kc)
    #pragma unroll
    for (int ct = 0; ct < 8; ++ct) {
      const bf16x8 bf = *(const bf16x8*)&wlds[((kc * 8 + ct) * 64 + l) * 8];
      aa[ct] = __builtin_amdgcn_mfma_f32_16x16x32_bf16(afa[kc], bf, aa[ct], 0, 0, 0);
      ab[ct] = __builtin_amdgcn_mfma_f32_16x16x32_bf16(afb[kc], bf, ab[ct], 0, 0, 0);
    }
  // relu -> slab (affine 272B-stride rows; wave-private region; imm-offset stores)
  #pragma unroll
  for (int rg = 0; rg < 4; ++rg) {
    ushort_t* rowpa = &slab[(w * 32 + 4 * g + rg) * HSTRIDE + li];
    ushort_t* rowpb = rowpa + 16 * HSTRIDE;
    #pragma unroll
    for (int ct = 0; ct < 8; ++ct) {
      rowpa[ct * 16] = f2b(fmaxf(aa[ct][rg], 0.f));
      rowpb[ct * 16] = f2b(fmaxf(ab[ct][rg], 0.f));
    }
  }
  #pragma unroll
  for (int ct = 0; ct < 8; ++ct) {
    const float bv = b2v[ct * 16 + li];
    aa[ct] = (f32x4){bv, bv, bv, bv};
    ab[ct] = aa[ct];
  }
  {
    const ushort_t* rowa = &slab[(w * 32 + li) * HSTRIDE + g * 8];
    const ushort_t* rowb = rowa + 16 * HSTRIDE;
    #pragma unroll
    for (int kc = 0; kc < 4; ++kc) {
      const bf16x8 hfa = *(const bf16x8*)(rowa + kc * 32);
      const bf16x8 hfb = *(const bf16x8*)(rowb + kc * 32);
      #pragma unroll
      for (int ct = 0; ct < 8; ++ct) {
        const bf16x8 bf = *(const bf16x8*)&wlds[16384 + ((kc * 8 + ct) * 64 + l) * 8];
        aa[ct] = __builtin_amdgcn_mfma_f32_16x16x32_bf16(hfa, bf, aa[ct], 0, 0, 0);
        ab[ct] = __builtin_amdgcn_mfma_f32_16x16x32_bf16(hfb, bf, ab[ct], 0, 0, 0);
      }
    }
  }
  #pragma unroll
  for (int grp = 0; grp < 2; ++grp) {
    f32x4* ac = grp ? ab : aa;
    float sc[4];
    #pragma unroll
    for (int rg = 0; rg < 4; ++rg) {
      float ssq = 0.f;
      #pragma unroll
      for (int ct = 0; ct < 8; ++ct) ssq += ac[ct][rg] * ac[ct][rg];
      ssq += __shfl_xor(ssq, 1);
      ssq += __shfl_xor(ssq, 2);
      ssq += __shfl_xor(ssq, 4);
      ssq += __shfl_xor(ssq, 8);
      sc[rg] = 1.f / fmaxf(sqrtf(ssq), 1e-12f);
    }
    #pragma unroll
    for (int rg = 0; rg < 4; ++rg) {
      ushort_t* rowp = &slab[(w * 32 + grp * 16 + 4 * g + rg) * HSTRIDE + li];
      #pragma unroll
      for (int ct = 0; ct < 8; ++ct)
        rowp[ct * 16] = f2b(ac[ct][rg] * sc[rg]);
    }
  }
  // coalesced copy-out of own 32 rows (strided slab -> dense global)
  {
    uint4* d4 = (uint4*)(zout + (size_t)(base + w * 32) * DDIM);
    const uint4* s4 = (const uint4*)slab;
    #pragma unroll
    for (int i = 0; i < 8; ++i) {
      const int e = l + 64 * i;                 // 512 uint4 chunks over 32 rows
      const int row = e >> 4, c = e & 15;
      d4[e] = s4[(w * 32 + row) * (HSTRIDE / 8) + c];
    }
  }
}

// ---- loss: R17 exactly (104 blocks x 512; slice in LDS; 1 atomic/block) ----
#define LROW_U4 17                           // 272 B row stride in uint4 units
__global__ __launch_bounds__(512)
void loss_kernel(const ushort_t* __restrict__ zb, float* __restrict__ out)
{
  __shared__ __align__(16) uint4 sl[SS * LROW_U4];     // 27200 B slice stage
  __shared__ float sterm[8];
  const int bid = blockIdx.x;            // 104 = chunk(13) x grp(8), grp fastest
  const int grp = bid & 7;               // XCD-affine under round-robin dispatch
  const int chunk = bid >> 3;
  const int typ = grp >> 2;
  const int vl  = grp & 3;
  const ushort_t* A  = zb + (size_t)(typ ? ROWS_A : 0) * DDIM;
  const ushort_t* Nb = zb + (size_t)(2 * ROWS_A + (typ ? ROWS_N : 0)) * DDIM;
  const ushort_t* SL = A + (size_t)(vl * 4 + vl) * SS * DDIM;  // anchor slice
  const int t = threadIdx.x, l = t & 63, w = t >> 6;
  const int tsub = l >> 3, eg = l & 7;
  const int s_raw = chunk * 8 + w;
  const bool act = (s_raw < SS);
  const int s = act ? s_raw : SS - 1;

  #pragma unroll
  for (int i = 0; i < 4; ++i) {
    const int c = i * 512 + t;                 // 1600 uint4 chunks
    if (c < SS * 16)
      sl[(c >> 4) * LROW_U4 + (c & 15)] = ((const uint4*)SL)[c];
  }

  const ushort_t* zs = SL + (size_t)s * DDIM;
  float zr[16];
  {
    const u16x8 v0 = *(const u16x8*)(zs + eg * 16);
    const u16x8 v1 = *(const u16x8*)(zs + eg * 16 + 8);
    #pragma unroll
    for (int j = 0; j < 8; ++j) { zr[j] = b2f(v0[j]); zr[j + 8] = b2f(v1[j]); }
  }

  float pe = 0.f, ne = 0.f;
  // target order: [0,50) cross | [50,53) pos | [53,152) within
  #pragma unroll
  for (int pass = 0; pass < 6; ++pass) {
    const int n = pass * 8 + tsub;
    const ushort_t* tp = Nb + (size_t)((vl * SS + s) * NNEGS + n) * DDIM;
    const u16x8 x0 = *(const u16x8*)(tp + eg * 16);
    const u16x8 x1 = *(const u16x8*)(tp + eg * 16 + 8);
    float d = 0.f;
    #pragma unroll
    for (int j = 0; j < 8; ++j) {
      d = fmaf(b2f(x0[j]), zr[j], d);
      d = fmaf(b2f(x1[j]), zr[j + 8], d);
    }
    d += __shfl_xor(d, 1);
    d += __shfl_xor(d, 2);
    d += __shfl_xor(d, 4);
    ne += __expf(d * INV_TEMP);
  }
  __syncthreads();                             // slice staged

  #pragma unroll
  for (int pass = 6; pass < 19; ++pass) {
    const int tt = pass * 8 + tsub;
    float d = 0.f;
    bool is_pos = false;
    if (tt >= 53) {                            // within-neg from LDS
      int j = tt - 53;
      int t2 = j + (j >= s ? 1 : 0);
      const uint4* rp = &sl[t2 * LROW_U4 + eg * 2];
      const u16x8 x0 = *(const u16x8*)rp;
      const u16x8 x1 = *(const u16x8*)(rp + 1);
      #pragma unroll
      for (int j2 = 0; j2 < 8; ++j2) {
        d = fmaf(b2f(x0[j2]), zr[j2], d);
        d = fmaf(b2f(x1[j2]), zr[j2 + 8], d);
      }
    } else {
      const ushort_t* tp;
      if (tt < 50) {
        tp = Nb + (size_t)((vl * SS + s) * NNEGS + tt) * DDIM;
      } else {
        const int kp = tt - 50;
        const int k = kp + (kp >= vl ? 1 : 0);
        tp = A + (size_t)((k * 4 + vl) * SS + s) * DDIM;
        is_pos = true;
      }
      const u16x8 x0 = *(const u16x8*)(tp + eg * 16);
      const u16x8 x1 = *(const u16x8*)(tp + eg * 16 + 8);
      #pragma unroll
      for (int j2 = 0; j2 < 8; ++j2) {
        d = fmaf(b2f(x0[j2]), zr[j2], d);
        d = fmaf(b2f(x1[j2]), zr[j2 + 8], d);
      }
    }
    d += __shfl_xor(d, 1);
    d += __shfl_xor(d, 2);
    d += __shfl_xor(d, 4);
    const float e = __expf(d * INV_TEMP);
    if (is_pos) pe += e; else ne += e;
  }
  pe += __shfl_xor(pe, 8);  ne += __shfl_xor(ne, 8);
  pe += __shfl_xor(pe, 16); ne += __shfl_xor(ne, 16);
  pe += __shfl_xor(pe, 32); ne += __shfl_xor(ne, 32);
  if (l == 0) sterm[w] = act ? -logf(pe / (pe + ne)) : 0.f;
  __syncthreads();
  if (t == 0) {
    float tot = 0.f;
    #pragma unroll
    for (int i = 0; i < 8; ++i) tot += sterm[i];
    atomicAdd(out, tot * (1.0f / 800.0f));
  }
}

extern "C" void kernel_launch(void* const* d_in, const int* in_sizes, int n_in,
                              void* d_out, int out_size, void* d_ws, size_t ws_size,
                              hipStream_t stream) {
  const float* emb_p = (const float*)d_in[0];
  const float* emb_c = (const float*)d_in[1];
  const float* W1    = (const float*)d_in[2];
  const float* b1    = (const float*)d_in[3];
  const float* W2    = (const float*)d_in[4];
  const float* b2    = (const float*)d_in[5];
  const void*  idx_p  = d_in[6];
  const void*  idx_c  = d_in[7];
  const void*  nidx_p = d_in[8];
  const void*  nidx_c = d_in[9];
  float* out = (float*)d_out;
  ushort_t* zrows = (ushort_t*)d_ws;

  proj_kernel<<<NBLK, 512, 0, stream>>>(
      emb_p, emb_c, W1, b1, W2, b2, idx_p, idx_c, nidx_p, nidx_c, zrows, out);
  loss_kernel<<<104, 512, 0, stream>>>(zrows, out);
}